// Round 1
// 417.201 us; speedup vs baseline: 1.0479x; 1.0479x over previous
//
#include <hip/hip_runtime.h>
#include <hip/hip_bf16.h>
#include <stdint.h>

typedef unsigned short u16;
typedef unsigned int   u32;

#define N_NODES 50000
#define N_EDGES 400000
#define DDIM    512
#define KTOT    1024          // fused K: [xb | meanNeg]
#define BM      128
#define BN      128
#define BK      64
#define NT      (KTOT / BK)   // 16 K-tiles
#define GRID_M  ((N_NODES + BM - 1) / BM)   // 391

typedef __attribute__((ext_vector_type(8))) __bf16 bf16x8;
typedef __attribute__((ext_vector_type(4))) float  f32x4;

// ---------- helpers ----------
__device__ __forceinline__ float bflo(u32 d) { return __builtin_bit_cast(float, d << 16); }
__device__ __forceinline__ float bfhi(u32 d) { return __builtin_bit_cast(float, d & 0xffff0000u); }
__device__ __forceinline__ u16 f2bf(float f) {
    u32 u = __builtin_bit_cast(u32, f);
    u32 r = u + 0x7fffu + ((u >> 16) & 1u);   // RNE; inputs finite
    return (u16)(r >> 16);
}
__device__ __forceinline__ u32 pack2(float a, float b) {
    return (u32)f2bf(a) | ((u32)f2bf(b) << 16);
}
__device__ __forceinline__ void gload_lds16(const void* g, void* l) {
    __builtin_amdgcn_global_load_lds(
        (const __attribute__((address_space(1))) void*)g,
        (__attribute__((address_space(3))) void*)l, 16, 0, 0);
}

// ---------- 0. x (f32) -> Acat[:, 0:512] (bf16, row stride 1024) ----------
__global__ void cvt_k(const float* __restrict__ x, u16* __restrict__ Acat) {
    int i = blockIdx.x * 256 + threadIdx.x;     // one thread = 8 elements
    int node = i >> 6, c8 = i & 63;             // 64 threads per node-row
    const float4* p = (const float4*)(x + (size_t)node * DDIM + c8 * 8);
    float4 a = p[0], b = p[1];
    uint4 o;
    o.x = pack2(a.x, a.y); o.y = pack2(a.z, a.w);
    o.z = pack2(b.x, b.y); o.w = pack2(b.z, b.w);
    *(uint4*)(Acat + (size_t)node * KTOT + c8 * 8) = o;
}

// ---------- 1. histogram of dst ----------
__global__ void hist_k(const int* __restrict__ dst, int* __restrict__ counts) {
    int e = blockIdx.x * 256 + threadIdx.x;
    if (e < N_EDGES) atomicAdd(&counts[dst[e]], 1);
}

// ---------- 2. three-phase exclusive scan (49 chunks of 1024) ----------
#define NCHUNK 49
__global__ __launch_bounds__(1024) void scanA_k(const int* __restrict__ counts, int* __restrict__ csum) {
    __shared__ int ws[16];
    int t = threadIdx.x, b = blockIdx.x;
    int i = b * 1024 + t;
    int v = (i < N_NODES) ? counts[i] : 0;
    for (int d = 32; d; d >>= 1) v += __shfl_down(v, d);
    if ((t & 63) == 0) ws[t >> 6] = v;
    __syncthreads();
    if (t < 16) {
        int s = ws[t];
        for (int d = 8; d; d >>= 1) s += __shfl_down(s, d);
        if (t == 0) csum[b] = s;
    }
}
__global__ void scanB_k(int* __restrict__ csum) {   // 64 threads, exclusive in-place
    int t = threadIdx.x;
    int v = (t < NCHUNK) ? csum[t] : 0;
    int s = v;
    for (int d = 1; d < 64; d <<= 1) { int u = __shfl_up(s, d); if (t >= d) s += u; }
    if (t < NCHUNK) csum[t] = s - v;
}
__global__ __launch_bounds__(1024) void scanC_k(const int* __restrict__ counts, const int* __restrict__ csum,
                                                int* __restrict__ offsets, int* __restrict__ cursor) {
    __shared__ int wsum[16];
    int t = threadIdx.x, b = blockIdx.x;
    int i = b * 1024 + t;
    int lane = t & 63, w = t >> 6;
    int v = (i < N_NODES) ? counts[i] : 0;
    int s = v;
    for (int d = 1; d < 64; d <<= 1) { int u = __shfl_up(s, d); if (lane >= d) s += u; }
    if (lane == 63) wsum[w] = s;
    __syncthreads();
    if (t < 16) {
        int ww = wsum[t], ss = ww;
        for (int d = 1; d < 16; d <<= 1) { int u = __shfl_up(ss, d); if (t >= d) ss += u; }
        wsum[t] = ss - ww;
    }
    __syncthreads();
    int excl = (s - v) + wsum[w] + csum[b];
    if (i < N_NODES) { offsets[i] = excl; cursor[i] = excl; }
}

// ---------- 3. fill CSR ----------
__global__ void fill_k(const int* __restrict__ src, const int* __restrict__ dst,
                       int* __restrict__ cursor, int* __restrict__ esrc) {
    int e = blockIdx.x * 256 + threadIdx.x;
    if (e < N_EDGES) {
        int d = dst[e];
        int p = atomicAdd(&cursor[d], 1);
        esrc[p] = src[e];
    }
}

// ---------- 4. prep weights: Wcat[n][k] = bf16(W1+W2), Wcat[n][512+k] = bf16(W2) ----------
__global__ void prepw_k(const float* __restrict__ W1, const float* __restrict__ W2,
                        const float* __restrict__ b1, const float* __restrict__ b2,
                        u16* __restrict__ Wcat, float* __restrict__ b12) {
    int idx = blockIdx.x * 256 + threadIdx.x;          // = k*512 + n
    int k = idx >> 9, n = idx & 511;
    float w1 = W1[idx], w2 = W2[idx];
    Wcat[(size_t)n * KTOT + k]       = f2bf(w1 + w2);
    Wcat[(size_t)n * KTOT + 512 + k] = f2bf(w2);
    if (idx < 512) b12[idx] = b1[idx] + b2[idx];
}

// ---------- 5. aggregate: Acat[:, 512:1024] = bf16(-mean) ----------
__device__ __forceinline__ void addrow(float* acc, uint4 v) {
    acc[0] += bflo(v.x); acc[1] += bfhi(v.x);
    acc[2] += bflo(v.y); acc[3] += bfhi(v.y);
    acc[4] += bflo(v.z); acc[5] += bfhi(v.z);
    acc[6] += bflo(v.w); acc[7] += bfhi(v.w);
}
__global__ __launch_bounds__(256) void agg_k(u16* Acat,
                                             const int* __restrict__ offsets,
                                             const int* __restrict__ counts,
                                             const int* __restrict__ esrc) {
    int nid = blockIdx.x * 4 + (threadIdx.x >> 6);
    if (nid >= N_NODES) return;
    int lane = threadIdx.x & 63;
    int off = offsets[nid], deg = counts[nid];
    float acc[8] = {0, 0, 0, 0, 0, 0, 0, 0};
    int e = 0;
    for (; e + 3 < deg; e += 4) {
        int s0 = esrc[off + e], s1 = esrc[off + e + 1];
        int s2 = esrc[off + e + 2], s3 = esrc[off + e + 3];
        uint4 v0 = *(const uint4*)(Acat + (size_t)s0 * KTOT + lane * 8);
        uint4 v1 = *(const uint4*)(Acat + (size_t)s1 * KTOT + lane * 8);
        uint4 v2 = *(const uint4*)(Acat + (size_t)s2 * KTOT + lane * 8);
        uint4 v3 = *(const uint4*)(Acat + (size_t)s3 * KTOT + lane * 8);
        addrow(acc, v0); addrow(acc, v1); addrow(acc, v2); addrow(acc, v3);
    }
    for (; e < deg; e++) {
        int s0 = esrc[off + e];
        addrow(acc, *(const uint4*)(Acat + (size_t)s0 * KTOT + lane * 8));
    }
    float scale = (deg > 0) ? (-1.0f / (float)deg) : 0.0f;
    uint4 o;
    o.x = pack2(acc[0] * scale, acc[1] * scale);
    o.y = pack2(acc[2] * scale, acc[3] * scale);
    o.z = pack2(acc[4] * scale, acc[5] * scale);
    o.w = pack2(acc[6] * scale, acc[7] * scale);
    *(uint4*)(Acat + (size_t)nid * KTOT + 512 + lane * 8) = o;
}

// ---------- 6. GEMM: out = Acat @ Wcat^T + b12 (K=1024, masked passthrough) ----------
// T3-minimum 2-phase pipeline: stage(t+1) issued BEFORE compute(t); one barrier/K-tile.
// LDS 64 KB (2 dbuf x (A 128x64 + B 128x64) bf16) -> 2 blocks/CU so drains overlap.
// Both-sides XOR swizzle (slot ^= row&7): linear gload_lds dest + pre-swizzled global
// source + swizzled ds_read -> minimum bank aliasing at 128-B LDS rows.
__global__ __launch_bounds__(256, 2) void gemm_k(const u16* __restrict__ Acat,
                                                 const float* __restrict__ x,
                                                 const u16* __restrict__ Wcat,
                                                 const float* __restrict__ b12,
                                                 const int* __restrict__ counts,
                                                 float* __restrict__ out) {
    __shared__ u16 As[2][BM * BK];
    __shared__ u16 Bs[2][BN * BK];

    // bijective XCD swizzle (m204): consecutive wg = 4 N-tiles of one A-panel -> same XCD L2
    const int nwg = gridDim.x;
    int orig = blockIdx.x;
    int xcd = orig & 7, loc = orig >> 3;
    int q8 = nwg >> 3, r8 = nwg & 7;
    int wg = (xcd < r8 ? xcd * (q8 + 1) : r8 * (q8 + 1) + (xcd - r8) * q8) + loc;
    const int m0 = (wg >> 2) * BM;
    const int n0 = (wg & 3) * BN;

    const int tid  = threadIdx.x;
    const int lane = tid & 63;
    const int wid  = tid >> 6;
    const int wm = wid >> 1, wn = wid & 1;
    const int quad = lane >> 4, lr = lane & 15;

    // staging geometry: per issue q, 256 threads load 32 rows x 128B; 8 threads/row
    const int srow = tid >> 3;                         // row within 32-row group
    const int so8  = (((tid & 7) ^ (srow & 7)) << 3);  // swizzled 16B slot -> u16 offset
    int arowg[4], browg[4];
    #pragma unroll
    for (int q = 0; q < 4; q++) {
        int r = q * 32 + srow;
        int ar = m0 + r; if (ar > N_NODES - 1) ar = N_NODES - 1;   // clamp M tail
        arowg[q] = ar;
        browg[q] = n0 + r;                                          // N=512 exact, no clamp
    }

    f32x4 acc[4][4] = {};

    auto stage = [&](u16* Asb, u16* Bsb, int t) {
        const int k0 = t * BK;
        #pragma unroll
        for (int q = 0; q < 4; q++) {
            gload_lds16(Acat + (size_t)arowg[q] * KTOT + k0 + so8,
                        Asb + q * 2048 + wid * 512);
            gload_lds16(Wcat + (size_t)browg[q] * KTOT + k0 + so8,
                        Bsb + q * 2048 + wid * 512);
        }
    };

    const int swb   = (lr & 7) << 4;                 // read-side swizzle (bytes)
    const int arow0 = (wm * 64 + lr) * 128;          // byte offsets
    const int brow0 = (wn * 64 + lr) * 128;

    auto compute = [&](const u16* Asb, const u16* Bsb) {
        bf16x8 af[2][4], bfr[2][4];
        #pragma unroll
        for (int ks = 0; ks < 2; ks++) {
            const int koff = (ks * 64 + quad * 16) ^ swb;
            #pragma unroll
            for (int i = 0; i < 4; i++)
                af[ks][i] = *(const bf16x8*)((const char*)Asb + arow0 + i * 2048 + koff);
            #pragma unroll
            for (int j = 0; j < 4; j++)
                bfr[ks][j] = *(const bf16x8*)((const char*)Bsb + brow0 + j * 2048 + koff);
        }
        #pragma unroll
        for (int ks = 0; ks < 2; ks++)
            #pragma unroll
            for (int i = 0; i < 4; i++)
                #pragma unroll
                for (int j = 0; j < 4; j++)
                    acc[i][j] = __builtin_amdgcn_mfma_f32_16x16x32_bf16(af[ks][i], bfr[ks][j], acc[i][j], 0, 0, 0);
    };

    stage(As[0], Bs[0], 0);
    __syncthreads();                                  // vmcnt(0) drain inside
    #pragma unroll 1
    for (int t = 0; t < NT; t += 2) {
        stage(As[1], Bs[1], t + 1);                   // prefetch overlaps compute below
        compute(As[0], Bs[0]);
        __syncthreads();
        if (t + 2 < NT) stage(As[0], Bs[0], t + 2);
        compute(As[1], Bs[1]);
        __syncthreads();
    }

    // epilogue: C/D layout col=lr, row=quad*4+r ; f32 output, zero-degree passthrough
    #pragma unroll
    for (int i = 0; i < 4; i++) {
        #pragma unroll
        for (int r = 0; r < 4; r++) {
            int grow = m0 + wm * 64 + i * 16 + quad * 4 + r;
            if (grow >= N_NODES) continue;
            int cnt = counts[grow];
            #pragma unroll
            for (int j = 0; j < 4; j++) {
                int gcol = n0 + wn * 64 + j * 16 + lr;
                float v;
                if (cnt > 0) v = acc[i][j][r] + b12[gcol];
                else         v = x[(size_t)grow * DDIM + gcol];   // exact passthrough
                out[(size_t)grow * DDIM + gcol] = v;
            }
        }
    }
}

// ---------- launch ----------
extern "C" void kernel_launch(void* const* d_in, const int* in_sizes, int n_in,
                              void* d_out, int out_size, void* d_ws, size_t ws_size,
                              hipStream_t stream) {
    const float* x  = (const float*)d_in[0];
    const int* src  = (const int*)d_in[1];
    const int* dst  = (const int*)d_in[2];
    const float* W1 = (const float*)d_in[3];
    const float* b1 = (const float*)d_in[4];
    const float* W2 = (const float*)d_in[5];
    const float* b2 = (const float*)d_in[6];
    float* out = (float*)d_out;

    char* ws = (char*)d_ws;
    size_t o = 0;
    auto alloc = [&](size_t bytes) { char* p = ws + o; o += (bytes + 255) & ~(size_t)255; return p; };
    int* counts   = (int*)alloc((size_t)N_NODES * 4);
    int* offsets  = (int*)alloc((size_t)N_NODES * 4);
    int* cursor   = (int*)alloc((size_t)N_NODES * 4);
    int* csum     = (int*)alloc((size_t)NCHUNK * 4);
    int* esrc     = (int*)alloc((size_t)N_EDGES * 4);
    u16* Wcat     = (u16*)alloc((size_t)512 * KTOT * 2);
    float* b12    = (float*)alloc((size_t)512 * 4);
    u16* Acat     = (u16*)alloc((size_t)N_NODES * KTOT * 2);   // [xb | meanNeg], ~102.4 MB
    (void)ws_size; (void)n_in; (void)in_sizes; (void)out_size;

    hipMemsetAsync(counts, 0, (size_t)N_NODES * 4, stream);
    cvt_k<<<(N_NODES * 64) / 256, 256, 0, stream>>>(x, Acat);
    hist_k<<<(N_EDGES + 255) / 256, 256, 0, stream>>>(dst, counts);
    scanA_k<<<NCHUNK, 1024, 0, stream>>>(counts, csum);
    scanB_k<<<1, 64, 0, stream>>>(csum);
    scanC_k<<<NCHUNK, 1024, 0, stream>>>(counts, csum, offsets, cursor);
    fill_k<<<(N_EDGES + 255) / 256, 256, 0, stream>>>(src, dst, cursor, esrc);
    prepw_k<<<(512 * 512) / 256, 256, 0, stream>>>(W1, W2, b1, b2, Wcat, b12);
    agg_k<<<(N_NODES + 3) / 4, 256, 0, stream>>>(Acat, offsets, counts, esrc);
    gemm_k<<<dim3(GRID_M * 4), 256, 0, stream>>>(Acat, x, Wcat, b12, counts, out);
}

// Round 2
// 407.930 us; speedup vs baseline: 1.0717x; 1.0227x over previous
//
#include <hip/hip_runtime.h>
#include <hip/hip_bf16.h>
#include <stdint.h>

typedef unsigned short u16;
typedef unsigned int   u32;

#define N_NODES 50000
#define N_EDGES 400000
#define DDIM    512
#define KTOT    1024          // fused K: [xb | meanNeg]
#define BM      256
#define BN      256
#define BK      64
#define NT      (KTOT / BK)   // 16 K-tiles
#define MTILES  ((N_NODES + BM - 1) / BM)   // 196
#define NTILES  (DDIM / BN)                 // 2
#define NWG     (MTILES * NTILES)           // 392 = 8*49 exactly

typedef __attribute__((ext_vector_type(8))) __bf16 bf16x8;
typedef __attribute__((ext_vector_type(4))) float  f32x4;

// ---------- helpers ----------
__device__ __forceinline__ float bflo(u32 d) { return __builtin_bit_cast(float, d << 16); }
__device__ __forceinline__ float bfhi(u32 d) { return __builtin_bit_cast(float, d & 0xffff0000u); }
__device__ __forceinline__ u16 f2bf(float f) {
    u32 u = __builtin_bit_cast(u32, f);
    u32 r = u + 0x7fffu + ((u >> 16) & 1u);   // RNE; inputs finite
    return (u16)(r >> 16);
}
__device__ __forceinline__ u32 pack2(float a, float b) {
    return (u32)f2bf(a) | ((u32)f2bf(b) << 16);
}
__device__ __forceinline__ void gload_lds16(const void* g, void* l) {
    __builtin_amdgcn_global_load_lds(
        (const __attribute__((address_space(1))) void*)g,
        (__attribute__((address_space(3))) void*)l, 16, 0, 0);
}

// ---------- 0. x (f32) -> Acat[:, 0:512] (bf16, row stride 1024) ----------
__global__ void cvt_k(const float* __restrict__ x, u16* __restrict__ Acat) {
    int i = blockIdx.x * 256 + threadIdx.x;     // one thread = 8 elements
    int node = i >> 6, c8 = i & 63;             // 64 threads per node-row
    const float4* p = (const float4*)(x + (size_t)node * DDIM + c8 * 8);
    float4 a = p[0], b = p[1];
    uint4 o;
    o.x = pack2(a.x, a.y); o.y = pack2(a.z, a.w);
    o.z = pack2(b.x, b.y); o.w = pack2(b.z, b.w);
    *(uint4*)(Acat + (size_t)node * KTOT + c8 * 8) = o;
}

// ---------- 1. histogram of dst ----------
__global__ void hist_k(const int* __restrict__ dst, int* __restrict__ counts) {
    int e = blockIdx.x * 256 + threadIdx.x;
    if (e < N_EDGES) atomicAdd(&counts[dst[e]], 1);
}

// ---------- 2. three-phase exclusive scan (49 chunks of 1024) ----------
#define NCHUNK 49
__global__ __launch_bounds__(1024) void scanA_k(const int* __restrict__ counts, int* __restrict__ csum) {
    __shared__ int ws[16];
    int t = threadIdx.x, b = blockIdx.x;
    int i = b * 1024 + t;
    int v = (i < N_NODES) ? counts[i] : 0;
    for (int d = 32; d; d >>= 1) v += __shfl_down(v, d);
    if ((t & 63) == 0) ws[t >> 6] = v;
    __syncthreads();
    if (t < 16) {
        int s = ws[t];
        for (int d = 8; d; d >>= 1) s += __shfl_down(s, d);
        if (t == 0) csum[b] = s;
    }
}
__global__ void scanB_k(int* __restrict__ csum) {   // 64 threads, exclusive in-place
    int t = threadIdx.x;
    int v = (t < NCHUNK) ? csum[t] : 0;
    int s = v;
    for (int d = 1; d < 64; d <<= 1) { int u = __shfl_up(s, d); if (t >= d) s += u; }
    if (t < NCHUNK) csum[t] = s - v;
}
__global__ __launch_bounds__(1024) void scanC_k(const int* __restrict__ counts, const int* __restrict__ csum,
                                                int* __restrict__ offsets, int* __restrict__ cursor) {
    __shared__ int wsum[16];
    int t = threadIdx.x, b = blockIdx.x;
    int i = b * 1024 + t;
    int lane = t & 63, w = t >> 6;
    int v = (i < N_NODES) ? counts[i] : 0;
    int s = v;
    for (int d = 1; d < 64; d <<= 1) { int u = __shfl_up(s, d); if (lane >= d) s += u; }
    if (lane == 63) wsum[w] = s;
    __syncthreads();
    if (t < 16) {
        int ww = wsum[t], ss = ww;
        for (int d = 1; d < 16; d <<= 1) { int u = __shfl_up(ss, d); if (t >= d) ss += u; }
        wsum[t] = ss - ww;
    }
    __syncthreads();
    int excl = (s - v) + wsum[w] + csum[b];
    if (i < N_NODES) { offsets[i] = excl; cursor[i] = excl; }
}

// ---------- 3. fill CSR ----------
__global__ void fill_k(const int* __restrict__ src, const int* __restrict__ dst,
                       int* __restrict__ cursor, int* __restrict__ esrc) {
    int e = blockIdx.x * 256 + threadIdx.x;
    if (e < N_EDGES) {
        int d = dst[e];
        int p = atomicAdd(&cursor[d], 1);
        esrc[p] = src[e];
    }
}

// ---------- 4. prep weights: Wcat[n][k] = bf16(W1+W2), Wcat[n][512+k] = bf16(W2) ----------
__global__ void prepw_k(const float* __restrict__ W1, const float* __restrict__ W2,
                        const float* __restrict__ b1, const float* __restrict__ b2,
                        u16* __restrict__ Wcat, float* __restrict__ b12) {
    int idx = blockIdx.x * 256 + threadIdx.x;          // = k*512 + n
    int k = idx >> 9, n = idx & 511;
    float w1 = W1[idx], w2 = W2[idx];
    Wcat[(size_t)n * KTOT + k]       = f2bf(w1 + w2);
    Wcat[(size_t)n * KTOT + 512 + k] = f2bf(w2);
    if (idx < 512) b12[idx] = b1[idx] + b2[idx];
}

// ---------- 5. aggregate: Acat[:, 512:1024] = bf16(-mean) ----------
__device__ __forceinline__ void addrow(float* acc, uint4 v) {
    acc[0] += bflo(v.x); acc[1] += bfhi(v.x);
    acc[2] += bflo(v.y); acc[3] += bfhi(v.y);
    acc[4] += bflo(v.z); acc[5] += bfhi(v.z);
    acc[6] += bflo(v.w); acc[7] += bfhi(v.w);
}
__global__ __launch_bounds__(256) void agg_k(u16* Acat,
                                             const int* __restrict__ offsets,
                                             const int* __restrict__ counts,
                                             const int* __restrict__ esrc) {
    int nid = blockIdx.x * 4 + (threadIdx.x >> 6);
    if (nid >= N_NODES) return;
    int lane = threadIdx.x & 63;
    int off = offsets[nid], deg = counts[nid];
    float acc[8] = {0, 0, 0, 0, 0, 0, 0, 0};
    int e = 0;
    for (; e + 3 < deg; e += 4) {
        int s0 = esrc[off + e], s1 = esrc[off + e + 1];
        int s2 = esrc[off + e + 2], s3 = esrc[off + e + 3];
        uint4 v0 = *(const uint4*)(Acat + (size_t)s0 * KTOT + lane * 8);
        uint4 v1 = *(const uint4*)(Acat + (size_t)s1 * KTOT + lane * 8);
        uint4 v2 = *(const uint4*)(Acat + (size_t)s2 * KTOT + lane * 8);
        uint4 v3 = *(const uint4*)(Acat + (size_t)s3 * KTOT + lane * 8);
        addrow(acc, v0); addrow(acc, v1); addrow(acc, v2); addrow(acc, v3);
    }
    for (; e < deg; e++) {
        int s0 = esrc[off + e];
        addrow(acc, *(const uint4*)(Acat + (size_t)s0 * KTOT + lane * 8));
    }
    float scale = (deg > 0) ? (-1.0f / (float)deg) : 0.0f;
    uint4 o;
    o.x = pack2(acc[0] * scale, acc[1] * scale);
    o.y = pack2(acc[2] * scale, acc[3] * scale);
    o.z = pack2(acc[4] * scale, acc[5] * scale);
    o.w = pack2(acc[6] * scale, acc[7] * scale);
    *(uint4*)(Acat + (size_t)nid * KTOT + 512 + lane * 8) = o;
}

// ---------- 6. GEMM: out = Acat @ Wcat^T + b12 (K=1024, masked passthrough) ----------
// 256x256 tile, 8 waves (2M x 4N), BK=64, counted-vmcnt pipeline (T3+T4) + T5 setprio.
// Per K-tile (4 phases): Ph1 reads ALL bf + af[m0-3,ks0]  -> barrier (B region dead)
//                        Ph2 stages B(t+2) into dead region + MFMA
//                        Ph3 reads remaining af            -> barrier (A region dead)
//                        Ph4 stages A(t+2) + MFMA          -> vmcnt(8) + s_barrier
// vmcnt(8) leaves tile t+2's 8 loads in flight across the barrier (never drain to 0).
// Both-sides XOR swizzle (slot ^= row&7): linear gload_lds dest + pre-swizzled global
// source + swizzled ds_read -> conflict-free (verified 0 conflicts in round 1).
#define WAITLGKM() do { asm volatile("s_waitcnt lgkmcnt(0)" ::: "memory"); \
                        __builtin_amdgcn_sched_barrier(0); } while (0)

__global__ __launch_bounds__(512, 2) void gemm_k(const u16* __restrict__ Acat,
                                                 const float* __restrict__ x,
                                                 const u16* __restrict__ Wcat,
                                                 const float* __restrict__ b12,
                                                 const int* __restrict__ counts,
                                                 float* __restrict__ out) {
    __shared__ u16 As[2][BM * BK];   // 2 x 32 KB
    __shared__ u16 Bs[2][BN * BK];   // 2 x 32 KB  (total 128 KB)

    // XCD swizzle: NWG = 392 = 8*49 exact -> each XCD gets 49 contiguous tiles.
    // tile_lin = m*2 + n so the two N-tiles of one A-panel are consecutive (same XCD L2).
    const int tlin = (blockIdx.x & 7) * (NWG / 8) + (blockIdx.x >> 3);
    const int m0 = (tlin >> 1) * BM;
    const int n0 = (tlin & 1) * BN;

    const int tid  = threadIdx.x;
    const int lane = tid & 63;
    const int wid  = tid >> 6;          // 0..7
    const int wm = wid >> 2, wn = wid & 3;
    const int quad = lane >> 4, lr = lane & 15;

    // staging: per gload issue, 512 threads cover 64 rows x 128 B (8 thr/row)
    const int so8u = (((tid & 7) ^ ((tid >> 3) & 7)) << 3);   // swizzled 16B slot (u16 units)
    int arowq[4], browq[4];
    #pragma unroll
    for (int q = 0; q < 4; q++) {
        int r = q * 64 + (tid >> 3);
        int ar = m0 + r; if (ar > N_NODES - 1) ar = N_NODES - 1;   // clamp M tail
        arowq[q] = ar;
        browq[q] = n0 + r;                                          // N=512 exact
    }

    auto stageA = [&](u16* A_c, int t) {
        const int k0 = t * BK;
        #pragma unroll
        for (int q = 0; q < 4; q++)
            gload_lds16(Acat + (size_t)arowq[q] * KTOT + k0 + so8u,
                        A_c + q * 4096 + wid * 512);
    };
    auto stageB = [&](u16* B_c, int t) {
        const int k0 = t * BK;
        #pragma unroll
        for (int q = 0; q < 4; q++)
            gload_lds16(Wcat + (size_t)browq[q] * KTOT + k0 + so8u,
                        B_c + q * 4096 + wid * 512);
    };

    const int swb = (lr & 7) << 4;      // read-side swizzle (bytes)
    auto ldA = [&](const u16* A_c, int mf, int ks) -> bf16x8 {
        int row = wm * 128 + mf * 16 + lr;
        return *(const bf16x8*)((const char*)A_c + row * 128 + ((ks * 64 + quad * 16) ^ swb));
    };
    auto ldB = [&](const u16* B_c, int nf, int ks) -> bf16x8 {
        int row = wn * 64 + nf * 16 + lr;
        return *(const bf16x8*)((const char*)B_c + row * 128 + ((ks * 64 + quad * 16) ^ swb));
    };

    f32x4 acc[8][4] = {};

    // prologue: tiles 0,1 -> bufs 0,1 (issue order: A0,B0,A1,B1 = 16 loads)
    stageA(As[0], 0); stageB(Bs[0], 0);
    stageA(As[1], 1); stageB(Bs[1], 1);
    asm volatile("s_waitcnt vmcnt(8)" ::: "memory");   // tile 0 landed; tile 1 in flight
    __builtin_amdgcn_sched_barrier(0);
    __builtin_amdgcn_s_barrier();

    #pragma unroll 1
    for (int t = 0; t < NT; ++t) {
        u16* A_c = As[t & 1];
        u16* B_c = Bs[t & 1];

        // ---- Ph1: all B-frags + af[m0-3][ks0]; MFMA (m0-3, ks0) ----
        bf16x8 bf0[4], bf1[4], af0[4];
        #pragma unroll
        for (int j = 0; j < 4; j++) bf0[j] = ldB(B_c, j, 0);
        #pragma unroll
        for (int j = 0; j < 4; j++) bf1[j] = ldB(B_c, j, 1);
        #pragma unroll
        for (int i = 0; i < 4; i++) af0[i] = ldA(A_c, i, 0);
        __builtin_amdgcn_s_setprio(1);
        #pragma unroll
        for (int i = 0; i < 4; i++)
            #pragma unroll
            for (int j = 0; j < 4; j++)
                acc[i][j] = __builtin_amdgcn_mfma_f32_16x16x32_bf16(af0[i], bf0[j], acc[i][j], 0, 0, 0);
        __builtin_amdgcn_s_setprio(0);
        WAITLGKM();                       // my B reads complete
        __builtin_amdgcn_s_barrier();     // all waves' B reads complete -> B region dead

        // ---- Ph2: stage B(t+2) into dead region; af[m4-7][ks0]; MFMA (m4-7, ks0) ----
        if (t + 2 < NT) stageB(B_c, t + 2);
        bf16x8 af1[4];
        #pragma unroll
        for (int i = 0; i < 4; i++) af1[i] = ldA(A_c, 4 + i, 0);
        __builtin_amdgcn_s_setprio(1);
        #pragma unroll
        for (int i = 0; i < 4; i++)
            #pragma unroll
            for (int j = 0; j < 4; j++)
                acc[4 + i][j] = __builtin_amdgcn_mfma_f32_16x16x32_bf16(af1[i], bf0[j], acc[4 + i][j], 0, 0, 0);
        __builtin_amdgcn_s_setprio(0);

        // ---- Ph3: remaining af (ks1, both halves); MFMA (m0-3, ks1) ----
        bf16x8 af2[4], af3[4];
        #pragma unroll
        for (int i = 0; i < 4; i++) af2[i] = ldA(A_c, i, 1);
        #pragma unroll
        for (int i = 0; i < 4; i++) af3[i] = ldA(A_c, 4 + i, 1);
        __builtin_amdgcn_s_setprio(1);
        #pragma unroll
        for (int i = 0; i < 4; i++)
            #pragma unroll
            for (int j = 0; j < 4; j++)
                acc[i][j] = __builtin_amdgcn_mfma_f32_16x16x32_bf16(af2[i], bf1[j], acc[i][j], 0, 0, 0);
        __builtin_amdgcn_s_setprio(0);
        WAITLGKM();                       // my A reads complete
        __builtin_amdgcn_s_barrier();     // all waves' A reads complete -> A region dead

        // ---- Ph4: stage A(t+2); MFMA (m4-7, ks1); counted wait ----
        if (t + 2 < NT) stageA(A_c, t + 2);
        __builtin_amdgcn_s_setprio(1);
        #pragma unroll
        for (int i = 0; i < 4; i++)
            #pragma unroll
            for (int j = 0; j < 4; j++)
                acc[4 + i][j] = __builtin_amdgcn_mfma_f32_16x16x32_bf16(af3[i], bf1[j], acc[4 + i][j], 0, 0, 0);
        __builtin_amdgcn_s_setprio(0);

        if (t < NT - 2) {
            // retire tile t+1 (oldest 8); leave tile t+2's 8 loads in flight
            asm volatile("s_waitcnt vmcnt(8)" ::: "memory");
            __builtin_amdgcn_sched_barrier(0);
            __builtin_amdgcn_s_barrier();
        } else if (t == NT - 2) {
            asm volatile("s_waitcnt vmcnt(0)" ::: "memory");   // drain: tile NT-1 landed
            __builtin_amdgcn_sched_barrier(0);
            __builtin_amdgcn_s_barrier();
        }
        // t == NT-1: fall through to epilogue
    }

    // epilogue: C/D layout col=lr, row=quad*4+r ; f32 output, zero-degree passthrough
    #pragma unroll
    for (int i = 0; i < 8; i++) {
        #pragma unroll
        for (int r = 0; r < 4; r++) {
            int grow = m0 + wm * 128 + i * 16 + quad * 4 + r;
            if (grow >= N_NODES) continue;
            int cnt = counts[grow];
            #pragma unroll
            for (int j = 0; j < 4; j++) {
                int gcol = n0 + wn * 64 + j * 16 + lr;
                float v;
                if (cnt > 0) v = acc[i][j][r] + b12[gcol];
                else         v = x[(size_t)grow * DDIM + gcol];   // exact passthrough
                out[(size_t)grow * DDIM + gcol] = v;
            }
        }
    }
}

// ---------- launch ----------
extern "C" void kernel_launch(void* const* d_in, const int* in_sizes, int n_in,
                              void* d_out, int out_size, void* d_ws, size_t ws_size,
                              hipStream_t stream) {
    const float* x  = (const float*)d_in[0];
    const int* src  = (const int*)d_in[1];
    const int* dst  = (const int*)d_in[2];
    const float* W1 = (const float*)d_in[3];
    const float* b1 = (const float*)d_in[4];
    const float* W2 = (const float*)d_in[5];
    const float* b2 = (const float*)d_in[6];
    float* out = (float*)d_out;

    char* ws = (char*)d_ws;
    size_t o = 0;
    auto alloc = [&](size_t bytes) { char* p = ws + o; o += (bytes + 255) & ~(size_t)255; return p; };
    int* counts   = (int*)alloc((size_t)N_NODES * 4);
    int* offsets  = (int*)alloc((size_t)N_NODES * 4);
    int* cursor   = (int*)alloc((size_t)N_NODES * 4);
    int* csum     = (int*)alloc((size_t)NCHUNK * 4);
    int* esrc     = (int*)alloc((size_t)N_EDGES * 4);
    u16* Wcat     = (u16*)alloc((size_t)512 * KTOT * 2);
    float* b12    = (float*)alloc((size_t)512 * 4);
    u16* Acat     = (u16*)alloc((size_t)N_NODES * KTOT * 2);   // [xb | meanNeg], ~102.4 MB
    (void)ws_size; (void)n_in; (void)in_sizes; (void)out_size;

    hipMemsetAsync(counts, 0, (size_t)N_NODES * 4, stream);
    cvt_k<<<(N_NODES * 64) / 256, 256, 0, stream>>>(x, Acat);
    hist_k<<<(N_EDGES + 255) / 256, 256, 0, stream>>>(dst, counts);
    scanA_k<<<NCHUNK, 1024, 0, stream>>>(counts, csum);
    scanB_k<<<1, 64, 0, stream>>>(csum);
    scanC_k<<<NCHUNK, 1024, 0, stream>>>(counts, csum, offsets, cursor);
    fill_k<<<(N_EDGES + 255) / 256, 256, 0, stream>>>(src, dst, cursor, esrc);
    prepw_k<<<(512 * 512) / 256, 256, 0, stream>>>(W1, W2, b1, b2, Wcat, b12);
    agg_k<<<(N_NODES + 3) / 4, 256, 0, stream>>>(Acat, offsets, counts, esrc);
    gemm_k<<<dim3(NWG), 512, 0, stream>>>(Acat, x, Wcat, b12, counts, out);
}